// Round 3
// baseline (866.442 us; speedup 1.0000x reference)
//
#include <hip/hip_runtime.h>
#include <math.h>

// CMCD sampler: single persistent cooperative kernel (32 blocks x 512 thr).
// Each block owns 16 particles; MLP h-tiles live in LDS (fragment-order) so
// the whole score network needs zero grid syncs. d2 stays in registers from
// gram to update. 18 grid syncs total via monotonic-counter barrier.

typedef __attribute__((ext_vector_type(8))) short short8;
typedef __attribute__((ext_vector_type(4))) float floatx4;
typedef unsigned int u32;
typedef unsigned short u16;

// ---- workspace byte offsets (~2.63 MB) ----
#define WS_BAR     0u         // u32 barrier counter (memset 0 each launch)
#define WS_BETAS   64u        // f32[16]
#define WS_NORMS   128u       // f32[512]
#define WS_TEP     2176u      // f32[4*8*512] te partial slabs
#define WS_G1P     67712u     // f32[8*8*512] t-MLP pre-act partials
#define WS_XBF     198784u    // u16[512*64]  x bf16 row-major
#define WS_XBFT0   264320u    // u16[64*512]  x^T bf16 parity 0
#define WS_XBFT1   329856u    // u16[64*512]  x^T bf16 parity 1
#define WS_INWT    395392u    // u16[512*64]  in_W^T
#define WS_OUTWT   460928u    // u16[64*512]  out_W^T
#define WS_HWT     526464u    // u16[3*512*512] h_W^T
#define WS_FINE    2099328u   // u32[2][65536] fine hist (parity)
#define WS_COARSE  2623616u   // u32[2][512]   coarse hist (parity)

__device__ __forceinline__ u16 f2bf(float f) {
  u32 u = __float_as_uint(f);
  u32 r = u + 0x7FFFu + ((u >> 16) & 1u);
  return (u16)(r >> 16);
}

// tanh-approx gelu (jax.nn.gelu default approximate=True)
__device__ __forceinline__ float gelu_f(float x) {
  float y = 0.7978845608028654f * (x + 0.044715f * x * x * x);
  float ay = fabsf(y);
  float e = __expf(-2.0f * ay);
  float t = (1.0f - e) / (1.0f + e);
  t = (y < 0.0f) ? -t : t;
  return 0.5f * x * (1.0f + t);
}

// write value for logical (row in [0,16), col in [0,512)) into MFMA-A
// fragment-order LDS: reader lane l gets A[m=l&15][k=kk*32+(l>>4)*8+j]
// at buf + kk*512 + l*8 + j  -> one clean ds_read_b128 per (wave,kk).
__device__ __forceinline__ void frag_write(u16* buf, int row, int col, u16 v) {
  int kk = col >> 5;
  int lanep = row + (((col >> 3) & 3) << 4);
  buf[kk * 512 + lanep * 8 + (col & 7)] = v;
}

// grid barrier: monotonic counter, no reset race. Cooperative launch
// guarantees co-residency (32 blocks << 256 CUs).
__device__ __forceinline__ void gsync(u32* bar, u32 target) {
  __syncthreads();
  if (threadIdx.x == 0) {
    __threadfence();  // make this block's plain stores device-visible
    __hip_atomic_fetch_add(bar, 1u, __ATOMIC_RELEASE, __HIP_MEMORY_SCOPE_AGENT);
    while (__hip_atomic_load(bar, __ATOMIC_ACQUIRE, __HIP_MEMORY_SCOPE_AGENT) < target) {
      __builtin_amdgcn_s_sleep(2);
    }
  }
  __syncthreads();
}

__global__ __launch_bounds__(512, 2) void mega(
    const float* __restrict__ particles, const float* __restrict__ noises,
    const float* __restrict__ grid_t, const float* __restrict__ eps,
    const float* __restrict__ mu, const float* __restrict__ phase,
    const float* __restrict__ in_W, const float* __restrict__ in_b,
    const float* __restrict__ t_W1, const float* __restrict__ t_b1,
    const float* __restrict__ t_W2, const float* __restrict__ t_b2,
    const float* __restrict__ h_W, const float* __restrict__ h_b,
    const float* __restrict__ out_W, const float* __restrict__ out_b,
    float* __restrict__ traj, char* __restrict__ ws)
{
  __shared__ __align__(16) u16 hbufA[8192];   // 16KB: L0/L2 out, then wexp
  __shared__ __align__(16) u16 hbufB[8192];   // 16KB: L1/L3(h3) out
  __shared__ __align__(16) float scr[5632];   // 22KB scratch (phase-aliased)

  u32* bar = (u32*)(ws + WS_BAR);
  float* BET = (float*)(ws + WS_BETAS);
  float* norms = (float*)(ws + WS_NORMS);
  float* TEP = (float*)(ws + WS_TEP);
  float* G1P = (float*)(ws + WS_G1P);
  u16* xbf = (u16*)(ws + WS_XBF);
  u16* xbfT0 = (u16*)(ws + WS_XBFT0);
  u16* xbfT1 = (u16*)(ws + WS_XBFT1);
  u16* inWT = (u16*)(ws + WS_INWT);
  u16* outWT = (u16*)(ws + WS_OUTWT);
  u16* hWT = (u16*)(ws + WS_HWT);
  u32* gfine = (u32*)(ws + WS_FINE);
  u32* gcoarse = (u32*)(ws + WS_COARSE);

  const int b = blockIdx.x;
  const int tid = threadIdx.x;
  const int wv = tid >> 6, lane = tid & 63;
  const int m = lane & 15, q = lane >> 4;
  u32 rnd = 0;

  // ================= P0: prep jobs (561 jobs over 32 blocks) =================
  for (int j = b; j < 561; j += 32) {
    if (j < 64) {                      // t-MLP pre-act partial, K-chain 128
      int slice = j >> 3, ii = j & 7;
      float* temb = scr;
      if (tid < 128) {
        int kglob = slice * 128 + tid;
        int kc = kglob & 511;
        float cf = 0.1f + (float)kc * (99.9f / 511.0f);
        float e = cf * (float)ii + phase[kc];
        temb[tid] = (kglob < 512) ? sinf(e) : cosf(e);
      }
      __syncthreads();
      float acc = (slice == 0) ? t_b1[tid] : 0.0f;
      const float* wp = t_W1 + (u32)slice * 128u * 512u + tid;
#pragma unroll 8
      for (int kk = 0; kk < 128; kk++) acc = fmaf(temb[kk], wp[kk * 512], acc);
      G1P[(slice * 8 + ii) * 512 + tid] = acc;
    } else if (j < 480) {              // LDS-tiled weight transposes -> bf16
      float* tile = scr;               // [2][32][33]
      int hh = tid >> 8, tt = tid & 255, tx = tt & 31, ty0 = tt >> 5;
      const float* src; u16* dst; int sstr, dstr;
      if (j < 448) {
        int ti = (j - 64) * 2 + hh;
        int l = ti >> 8, rem = ti & 255, kt = rem >> 4, ct = rem & 15;
        src = h_W + l * 262144 + kt * 32 * 512 + ct * 32; sstr = 512;
        dst = hWT + l * 262144 + ct * 32 * 512 + kt * 32; dstr = 512;
      } else if (j < 464) {
        int ti = (j - 448) * 2 + hh;
        int kt = ti >> 4, ct = ti & 15;
        src = in_W + kt * 32 * 512 + ct * 32; sstr = 512;
        dst = inWT + ct * 32 * 64 + kt * 32; dstr = 64;
      } else {
        int ti = (j - 464) * 2 + hh;
        int ct = ti >> 4, kt = ti & 15;
        src = out_W + kt * 32 * 64 + ct * 32; sstr = 64;
        dst = outWT + ct * 32 * 512 + kt * 32; dstr = 512;
      }
#pragma unroll
      for (int r = 0; r < 4; r++) { int ty = ty0 + r * 8; tile[(hh * 32 + ty) * 33 + tx] = src[ty * sstr + tx]; }
      __syncthreads();
#pragma unroll
      for (int r = 0; r < 4; r++) { int ty = ty0 + r * 8; dst[ty * dstr + tx] = f2bf(tile[(hh * 32 + tx) * 33 + ty]); }
    } else if (j == 480) {             // norms + betas + coarse-hist zero
      { float s = 0.f; const float* xr = particles + tid * 64;
#pragma unroll 8
        for (int d = 0; d < 64; d++) { float v = xr[d]; s = fmaf(v, v, s); }
        norms[tid] = s; }
      gcoarse[tid] = 0u; gcoarse[512 + tid] = 0u;
      if (tid == 0) {
        float sig[8]; float tot = 0.f;
        for (int k2 = 0; k2 < 8; k2++) { sig[k2] = 1.0f / (1.0f + __expf(-grid_t[k2])); tot += sig[k2]; }
        float cum = 0.f; BET[0] = 0.f;
        for (int k2 = 0; k2 < 8; k2++) { cum += sig[k2]; BET[k2 + 1] = cum / tot; }
      }
    } else if (j < 497) {              // x copies: traj row0, xbf, xbfT0
      int jj = j - 481;
#pragma unroll
      for (int k2 = 0; k2 < 4; k2++) {
        u32 e = (u32)jj * 2048u + (u32)(k2 * 512) + (u32)tid;
        float v = particles[e];
        traj[e] = v;
        u16 bv = f2bf(v);
        xbf[e] = bv;
        xbfT0[(e & 63u) * 512u + (e >> 6)] = bv;
      }
    } else {                           // fine hist zero (both parities)
      int jj = j - 497;
#pragma unroll
      for (int k2 = 0; k2 < 4; k2++) gfine[(u32)jj * 2048u + (u32)(k2 * 512) + (u32)tid] = 0u;
    }
    __syncthreads();
  }
  gsync(bar, 32u * (++rnd));

  // ================= P0b: te partial slabs (1 job per block) ================
  {
    int ii = b >> 2, kq = b & 3;
    float* g1 = scr;
    if (tid < 128) {
      int kglob = kq * 128 + tid;
      float s = 0.f;
#pragma unroll
      for (int sl = 0; sl < 8; sl++) s += G1P[(sl * 8 + ii) * 512 + kglob];
      g1[tid] = gelu_f(s);
    }
    __syncthreads();
    float acc = (kq == 0) ? (t_b2[tid] + in_b[tid]) : 0.0f;
    const float* wp = t_W2 + (u32)kq * 128u * 512u + tid;
#pragma unroll 8
    for (int kk = 0; kk < 128; kk++) acc = fmaf(g1[kk], wp[kk * 512], acc);
    TEP[(kq * 8 + ii) * 512 + tid] = acc;
  }
  gsync(bar, 32u * (++rnd));

  // ================= main loop: block owns rows [r0, r0+16) ================
  const int r0 = b * 16;
  for (int step = 0; step < 8; step++) {
    const int p = step & 1;
    const u16* xT_in = p ? xbfT1 : xbfT0;
    u16* xT_out = p ? xbfT0 : xbfT1;
    const float* x_old = traj + step * 32768;
    float* x_new = traj + (step + 1) * 32768;
    const float* noise_i = noises + step * 32768;

    // ---- gram: d2 for 16 own rows x all 512 cols; d2 stays in regs ----
    u32* lco = (u32*)scr;
    lco[tid] = 0u;
    __syncthreads();
    floatx4 d2r[4];
    {
      short8 a0 = *(const short8*)(xbf + (r0 + m) * 64 + q * 8);
      short8 a1 = *(const short8*)(xbf + (r0 + m) * 64 + 32 + q * 8);
      float nr[4];
#pragma unroll
      for (int rg = 0; rg < 4; rg++) nr[rg] = norms[r0 + q * 4 + rg];
#pragma unroll
      for (int t4 = 0; t4 < 4; t4++) {
        int c0g = (wv * 4 + t4) * 16;
        floatx4 acc = {0.f, 0.f, 0.f, 0.f};
        short8 b0 = *(const short8*)(xbf + (c0g + m) * 64 + q * 8);
        short8 b1 = *(const short8*)(xbf + (c0g + m) * 64 + 32 + q * 8);
        acc = __builtin_amdgcn_mfma_f32_16x16x32_bf16(a0, b0, acc, 0, 0, 0);
        acc = __builtin_amdgcn_mfma_f32_16x16x32_bf16(a1, b1, acc, 0, 0, 0);
        float nc = norms[c0g + m];
#pragma unroll
        for (int rg = 0; rg < 4; rg++) {
          float v = nr[rg] + nc - 2.0f * acc[rg];
          d2r[t4][rg] = v;
          int bin = (int)(v * 64.0f);
          bin = bin < 0 ? 0 : (bin > 65535 ? 65535 : bin);
          atomicAdd(&gfine[p * 65536 + bin], 1u);
          atomicAdd(&lco[bin >> 7], 1u);
        }
      }
    }
    __syncthreads();
    atomicAdd(&gcoarse[p * 512 + tid], lco[tid]);
    gsync(bar, 32u * (++rnd));          // hist complete device-wide

    // ---- median (every block, from coarse+fine hists) ----
    float inv_ht;
    {
      u32* scan = (u32*)scr;            // 512
      u32* fsc = (u32*)scr + 512;       // 128
      float* mret = scr + 768;          // dmed[2], inv_ht at [2]
      u32* cbs = (u32*)scr + 772;       // cb[2]
      u32 cnt = gcoarse[p * 512 + tid];
      scan[tid] = cnt;
      __syncthreads();
      for (int off = 1; off < 512; off <<= 1) {
        u32 add = (tid >= off) ? scan[tid - off] : 0u;
        __syncthreads();
        scan[tid] += add;
        __syncthreads();
      }
      u32 hi = scan[tid], lo = hi - cnt;
#pragma unroll
      for (int tr = 0; tr < 2; tr++) {
        u32 R = 131071u + (u32)tr;
        if (R >= lo && R < hi) cbs[tr] = (u32)tid;
      }
      __syncthreads();
#pragma unroll 1
      for (int tr = 0; tr < 2; tr++) {
        u32 R = 131071u + (u32)tr;
        u32 cb = cbs[tr];
        u32 base = (cb > 0) ? scan[cb - 1] : 0u;
        u32 fcnt = 0u;
        if (tid < 128) { fcnt = gfine[p * 65536 + cb * 128 + tid]; fsc[tid] = fcnt; }
        __syncthreads();
        for (int off = 1; off < 128; off <<= 1) {
          u32 add = 0u;
          if (tid < 128 && tid >= off) add = fsc[tid - off];
          __syncthreads();
          if (tid < 128) fsc[tid] += add;
          __syncthreads();
        }
        if (tid < 128) {
          u32 fhi = base + fsc[tid], flo = fhi - fcnt;
          if (R >= flo && R < fhi) {
            float d2v = ((float)(cb * 128 + (u32)tid) + ((float)(R - flo) + 0.5f) / (float)fcnt) * (1.0f / 64.0f);
            mret[tr] = sqrtf(fmaxf(d2v, 1e-12f));
          }
        }
        __syncthreads();
      }
      if (tid == 0) {
        float md = 0.5f * (mret[0] + mret[1]);
        mret[2] = 6.2383246250395075f / (md * md);   // log(512)/h_t = 1/ht
      }
      __syncthreads();
      inv_ht = mret[2];
    }

    // ---- L0: h0 = gelu(x @ in_W + te) -> hbufA (frag order) ----
    {
      floatx4 acc[4] = {{0,0,0,0},{0,0,0,0},{0,0,0,0},{0,0,0,0}};
      short8 a0 = *(const short8*)(xbf + (r0 + m) * 64 + q * 8);
      short8 a1 = *(const short8*)(xbf + (r0 + m) * 64 + 32 + q * 8);
#pragma unroll
      for (int t4 = 0; t4 < 4; t4++) {
        int c0g = (wv * 4 + t4) * 16;
        short8 b0 = *(const short8*)(inWT + (c0g + m) * 64 + q * 8);
        short8 b1 = *(const short8*)(inWT + (c0g + m) * 64 + 32 + q * 8);
        acc[t4] = __builtin_amdgcn_mfma_f32_16x16x32_bf16(a0, b0, acc[t4], 0, 0, 0);
        acc[t4] = __builtin_amdgcn_mfma_f32_16x16x32_bf16(a1, b1, acc[t4], 0, 0, 0);
      }
#pragma unroll
      for (int t4 = 0; t4 < 4; t4++) {
        int col = (wv * 4 + t4) * 16 + m;
        float bv = TEP[step * 512 + col] + TEP[4096 + step * 512 + col]
                 + TEP[8192 + step * 512 + col] + TEP[12288 + step * 512 + col];
#pragma unroll
        for (int rg = 0; rg < 4; rg++)
          frag_write(hbufA, q * 4 + rg, col, f2bf(gelu_f(acc[t4][rg] + bv)));
      }
    }
    __syncthreads();

    // ---- L1..L3: h = gelu(h @ h_W[l]); A from LDS, B streamed from L2 ----
    {
      u16* Abuf = hbufA; u16* Obuf = hbufB;
#pragma unroll 1
      for (int l = 0; l < 3; l++) {
        const u16* WT = hWT + l * 262144;
        const float* bias = h_b + l * 512;
        floatx4 acc[4] = {{0,0,0,0},{0,0,0,0},{0,0,0,0},{0,0,0,0}};
#pragma unroll 4
        for (int kk = 0; kk < 16; kk++) {
          short8 a = *(const short8*)(Abuf + kk * 512 + lane * 8);
#pragma unroll
          for (int t4 = 0; t4 < 4; t4++) {
            int c0g = (wv * 4 + t4) * 16;
            short8 bb = *(const short8*)(WT + (c0g + m) * 512 + kk * 32 + q * 8);
            acc[t4] = __builtin_amdgcn_mfma_f32_16x16x32_bf16(a, bb, acc[t4], 0, 0, 0);
          }
        }
#pragma unroll
        for (int t4 = 0; t4 < 4; t4++) {
          int col = (wv * 4 + t4) * 16 + m;
          float bv = bias[col];
#pragma unroll
          for (int rg = 0; rg < 4; rg++)
            frag_write(Obuf, q * 4 + rg, col, f2bf(gelu_f(acc[t4][rg] + bv)));
        }
        __syncthreads();
        u16* tmp = Abuf; Abuf = Obuf; Obuf = tmp;
      }
    }
    // now: hbufB = h3, hbufA dead

    // ---- update: wexp, score & S1 GEMMs, softmax, integrate ----
    {
      float* sc_s = scr;            // [16][64]
      float* s1_s = scr + 1024;     // [16][64]
      float* combS = scr + 2048;    // [4][64][4]
      float* combR = scr + 3072;
      float* wm = scr + 4096;       // [16][64]
      float* comp = scr + 5120;     // [16][8]
      float* w8 = scr + 5248;       // [16][8]
      float* s0p = scr + 5376;      // [16][8]
      float* s0_s = scr + 5504;     // [16]

      // wexp (bf16, frag order into hbufA) + per-row s0 partials
      float s0l[4] = {0.f, 0.f, 0.f, 0.f};
#pragma unroll
      for (int t4 = 0; t4 < 4; t4++) {
        int c0g = (wv * 4 + t4) * 16;
#pragma unroll
        for (int rg = 0; rg < 4; rg++) {
          float w = __expf(-d2r[t4][rg] * inv_ht);
          s0l[rg] += w;
          frag_write(hbufA, q * 4 + rg, c0g + m, f2bf(w));
        }
      }
#pragma unroll
      for (int off = 1; off < 16; off <<= 1)
#pragma unroll
        for (int rg = 0; rg < 4; rg++) s0l[rg] += __shfl_xor(s0l[rg], off);
      if (m == 0)
#pragma unroll
        for (int rg = 0; rg < 4; rg++) s0p[(q * 4 + rg) * 8 + wv] = s0l[rg];
      __syncthreads();

      // score (h3 @ out_W^T) and S1 (wexp @ x) with (ct, kh) K-split
      int ct = wv & 3, kh = wv >> 2, c0 = ct * 16;
      floatx4 accS = {0.f, 0.f, 0.f, 0.f}, accR = {0.f, 0.f, 0.f, 0.f};
#pragma unroll
      for (int kk = kh * 8; kk < kh * 8 + 8; kk++) {
        short8 a = *(const short8*)(hbufB + kk * 512 + lane * 8);
        short8 bw = *(const short8*)(outWT + (c0 + m) * 512 + kk * 32 + q * 8);
        accS = __builtin_amdgcn_mfma_f32_16x16x32_bf16(a, bw, accS, 0, 0, 0);
        short8 aw = *(const short8*)(hbufA + kk * 512 + lane * 8);
        short8 bx = *(const short8*)(xT_in + (c0 + m) * 512 + kk * 32 + q * 8);
        accR = __builtin_amdgcn_mfma_f32_16x16x32_bf16(aw, bx, accR, 0, 0, 0);
      }
      if (kh) {
#pragma unroll
        for (int rg = 0; rg < 4; rg++) {
          combS[(ct * 64 + lane) * 4 + rg] = accS[rg];
          combR[(ct * 64 + lane) * 4 + rg] = accR[rg];
        }
      }
      __syncthreads();
      if (!kh) {
        int col = c0 + m;
        float ob = out_b[col];
#pragma unroll
        for (int rg = 0; rg < 4; rg++) {
          sc_s[(q * 4 + rg) * 64 + col] = accS[rg] + combS[(ct * 64 + lane) * 4 + rg] + ob;
          s1_s[(q * 4 + rg) * 64 + col] = accR[rg] + combR[(ct * 64 + lane) * 4 + rg];
        }
      }
      if (tid < 16) {
        float s = 0.f;
#pragma unroll
        for (int w2 = 0; w2 < 8; w2++) s += s0p[tid * 8 + w2];
        s0_s[tid] = s;
      }
      if (tid < 128) {                 // comp[r][mm] (softmax const cancels)
        int r = tid >> 3, mm = tid & 7;
        const float* xr = x_old + (r0 + r) * 64;
        const float* mr = mu + mm * 64;
        float s = 0.f;
#pragma unroll 8
        for (int d = 0; d < 64; d++) { float df = xr[d] - mr[d]; s = fmaf(df, df, s); }
        comp[r * 8 + mm] = -0.5f * s;
      }
      __syncthreads();
      if (tid < 16) {
        float mx = comp[tid * 8];
        for (int j2 = 1; j2 < 8; j2++) mx = fmaxf(mx, comp[tid * 8 + j2]);
        float sm = 0.f; float e[8];
        for (int j2 = 0; j2 < 8; j2++) { e[j2] = __expf(comp[tid * 8 + j2] - mx); sm += e[j2]; }
        float inv = 1.0f / sm;
        for (int j2 = 0; j2 < 8; j2++) w8[tid * 8 + j2] = e[j2] * inv;
      }
      __syncthreads();
      if (tid < 256) {
        int r = tid >> 4, db = (tid & 15) * 4;
        for (int j2 = 0; j2 < 4; j2++) {
          float a2 = 0.f;
          for (int mm = 0; mm < 8; mm++) a2 = fmaf(w8[r * 8 + mm], mu[mm * 64 + db + j2], a2);
          wm[r * 64 + db + j2] = a2;
        }
      }
      __syncthreads();
      if (tid < 256) {
        float tb = BET[step];
        float dt = eps[0];
        float sq = sqrtf(2.0f * dt);
        int r = tid >> 4, db = (tid & 15) * 4;
        int grow = r0 + r;
        float s0r = s0_s[r];
        float cR = -0.1f * inv_ht;
        float nn = 0.f;
#pragma unroll
        for (int j2 = 0; j2 < 4; j2++) {
          float xv = x_old[grow * 64 + db + j2];
          float g = -xv + tb * wm[r * 64 + db + j2];              // grad log pi
          float rep = cR * (xv * s0r - s1_s[r * 64 + db + j2]);   // repel
          float nv = xv + dt * (g - sc_s[r * 64 + db + j2]) - dt * rep
                   + sq * noise_i[grow * 64 + db + j2];
          x_new[grow * 64 + db + j2] = nv;
          u16 bv = f2bf(nv);
          xbf[grow * 64 + db + j2] = bv;
          xT_out[(db + j2) * 512 + grow] = bv;
          nn = fmaf(nv, nv, nn);
        }
#pragma unroll
        for (int off = 1; off < 16; off <<= 1) nn += __shfl_xor(nn, off);
        if ((tid & 15) == 0) norms[grow] = nn;
      }
      // zero other-parity hists for step+1 (safe: its readers finished
      // before the end-of-step barrier of step-1)
      int po = p ^ 1;
#pragma unroll
      for (int k2 = 0; k2 < 4; k2++) gfine[po * 65536 + b * 2048 + k2 * 512 + tid] = 0u;
      if (tid < 16) gcoarse[po * 512 + b * 16 + tid] = 0u;
    }
    gsync(bar, 32u * (++rnd));          // new x, norms, xT visible
  }
}

extern "C" void kernel_launch(void* const* d_in, const int* in_sizes, int n_in,
                              void* d_out, int out_size, void* d_ws, size_t ws_size,
                              hipStream_t stream) {
  (void)in_sizes; (void)n_in; (void)out_size; (void)ws_size;
  const float* particles    = (const float*)d_in[0];
  const float* noises       = (const float*)d_in[1];
  const float* grid_t       = (const float*)d_in[2];
  const float* eps          = (const float*)d_in[3];
  const float* target_means = (const float*)d_in[4];
  const float* phase        = (const float*)d_in[5];
  const float* in_W         = (const float*)d_in[6];
  const float* in_b         = (const float*)d_in[7];
  const float* t_W1         = (const float*)d_in[8];
  const float* t_b1         = (const float*)d_in[9];
  const float* t_W2         = (const float*)d_in[10];
  const float* t_b2         = (const float*)d_in[11];
  const float* h_W          = (const float*)d_in[12];
  const float* h_b          = (const float*)d_in[13];
  const float* out_W        = (const float*)d_in[14];
  const float* out_b        = (const float*)d_in[15];
  float* traj = (float*)d_out;
  char* ws = (char*)d_ws;

  hipMemsetAsync(ws + WS_BAR, 0, 64, stream);   // barrier counter = 0

  void* args[] = {
    (void*)&particles, (void*)&noises, (void*)&grid_t, (void*)&eps,
    (void*)&target_means, (void*)&phase, (void*)&in_W, (void*)&in_b,
    (void*)&t_W1, (void*)&t_b1, (void*)&t_W2, (void*)&t_b2,
    (void*)&h_W, (void*)&h_b, (void*)&out_W, (void*)&out_b,
    (void*)&traj, (void*)&ws
  };
  hipLaunchCooperativeKernel((void*)mega, dim3(32), dim3(512), args, 0, stream);
}